// Round 1
// baseline (441.329 us; speedup 1.0000x reference)
//
#include <hip/hip_runtime.h>

typedef short bf16x8 __attribute__((ext_vector_type(8)));
typedef float f32x4 __attribute__((ext_vector_type(4)));

#define AS1 __attribute__((address_space(1)))
#define AS3 __attribute__((address_space(3)))

__device__ __forceinline__ void gld16(void* lds, const void* g) {
  __builtin_amdgcn_global_load_lds((const AS1 unsigned int*)g,
                                   (AS3 unsigned int*)lds, 16, 0, 0);
}

__device__ __forceinline__ unsigned short f2bf(float f) {
  union { float f; unsigned int u; } c; c.f = f;
  return (unsigned short)((c.u + 0x7FFFu + ((c.u >> 16) & 1u)) >> 16);
}

// ---------------- fp32 -> bf16 conversion ----------------
__global__ void cvt_kernel(const float4* __restrict__ in, ushort4* __restrict__ out, int n4) {
  int i = blockIdx.x * blockDim.x + threadIdx.x;
  int stride = gridDim.x * blockDim.x;
  for (; i < n4; i += stride) {
    float4 v = in[i];
    ushort4 o;
    o.x = f2bf(v.x); o.y = f2bf(v.y); o.z = f2bf(v.z); o.w = f2bf(v.w);
    out[i] = o;
  }
}

// ---------------- NT GEMM: out[m][n] = (sum_k A[m][k]*W[n][k] + bias[n]) * scale ----
// A: [M][K] bf16 row-major, W: [N][K] bf16 row-major.
// 128x128 tile, BK=32, 256 threads (4 waves, 2x2), mfma_f32_16x16x32_bf16.
__global__ __launch_bounds__(256) void gemm_bt_kernel(
    const unsigned short* __restrict__ A,
    const unsigned short* __restrict__ W,
    const float* __restrict__ bias,
    unsigned short* __restrict__ outB,  // bf16 output (or null)
    float* __restrict__ outF,           // f32 output (or null)
    int M, int N, int K, float scale)
{
  __shared__ unsigned short As[4 * 128 * 8];  // [kblk][row][8]
  __shared__ unsigned short Bs[4 * 128 * 8];

  const int tid = threadIdx.x;
  const int lane = tid & 63;
  const int w = tid >> 6;
  const int wr = (w >> 1) * 64;
  const int wc = (w & 1) * 64;
  const int lrow = lane & 15;
  const int lk = lane >> 4;
  const long m0 = (long)blockIdx.y * 128;
  const long n0 = (long)blockIdx.x * 128;

  f32x4 acc[4][4] = {};

  const int c0 = tid, c1 = tid + 256;
  const unsigned short* Ag0 = A + (m0 + (c0 & 127)) * (long)K + (c0 >> 7) * 8;
  const unsigned short* Ag1 = A + (m0 + (c1 & 127)) * (long)K + (c1 >> 7) * 8;
  const unsigned short* Wg0 = W + (n0 + (c0 & 127)) * (long)K + (c0 >> 7) * 8;
  const unsigned short* Wg1 = W + (n0 + (c1 & 127)) * (long)K + (c1 >> 7) * 8;
  unsigned short* Al0 = As + c0 * 8;
  unsigned short* Al1 = As + c1 * 8;
  unsigned short* Bl0 = Bs + c0 * 8;
  unsigned short* Bl1 = Bs + c1 * 8;

  const int arow = wr + lrow;
  const int brow = wc + lrow;

  for (int kt = 0; kt < K; kt += 32) {
    gld16(Al0, Ag0 + kt);
    gld16(Al1, Ag1 + kt);
    gld16(Bl0, Wg0 + kt);
    gld16(Bl1, Wg1 + kt);
    __syncthreads();  // drains vmcnt before barrier (compiler-enforced)

    bf16x8 af[4], bfr[4];
#pragma unroll
    for (int i = 0; i < 4; ++i)
      af[i] = *(const bf16x8*)(As + (lk * 128 + arow + i * 16) * 8);
#pragma unroll
    for (int j = 0; j < 4; ++j)
      bfr[j] = *(const bf16x8*)(Bs + (lk * 128 + brow + j * 16) * 8);
#pragma unroll
    for (int i = 0; i < 4; ++i)
#pragma unroll
      for (int j = 0; j < 4; ++j)
        acc[i][j] = __builtin_amdgcn_mfma_f32_16x16x32_bf16(af[i], bfr[j], acc[i][j], 0, 0, 0);
    __syncthreads();
  }

#pragma unroll
  for (int j = 0; j < 4; ++j) {
    const long col = n0 + wc + j * 16 + lrow;
    const float bv = bias[col];
#pragma unroll
    for (int i = 0; i < 4; ++i) {
#pragma unroll
      for (int r = 0; r < 4; ++r) {
        const long row = m0 + wr + i * 16 + lk * 4 + r;
        float v = (acc[i][j][r] + bv) * scale;
        if (outF) outF[row * (long)N + col] = v;
        else      outB[row * (long)N + col] = f2bf(v);
      }
    }
  }
}

// ---------------- Flash attention ----------------
// Q,K,V: [B][Seq][1024] bf16 (head h at channels h*64..h*64+63). Q pre-scaled by 1/8.
// Grid: (N/64, H, B), 256 threads (4 waves; wave w owns q-rows w*16..w*16+15).
__global__ __launch_bounds__(256) void attn_kernel(
    const unsigned short* __restrict__ Q,
    const unsigned short* __restrict__ K,
    const unsigned short* __restrict__ V,
    unsigned short* __restrict__ Y)
{
  __shared__ unsigned short Qs[8 * 64 * 8];   // [dblk][row][8]
  __shared__ unsigned short Ks[8 * 64 * 8];   // [dblk][t][8]
  __shared__ unsigned short Vt[64 * 72];      // [d][t] padded
  __shared__ float Ss[64 * 66];               // [q][t] padded
  __shared__ unsigned short Ps[64 * 72];      // [q][t] padded, bf16
  __shared__ float mrun[64], lrun[64], alphas[64];

  const int tid = threadIdx.x;
  const int lane = tid & 63;
  const int w = tid >> 6;
  const int lrow = lane & 15;
  const int lk = lane >> 4;
  const int b = blockIdx.z, h = blockIdx.y, qt = blockIdx.x;
  const long C = 1024, T = 2048, NQ = 2048;

  const unsigned short* Qg = Q + ((long)b * NQ + qt * 64) * C + h * 64;
  const unsigned short* Kg0 = K + (long)b * T * C + h * 64;
  const unsigned short* Vg0 = V + (long)b * T * C + h * 64;

  {
    int c = tid;
    gld16(Qs + c * 8, Qg + (long)(c & 63) * C + (c >> 6) * 8);
    c = tid + 256;
    gld16(Qs + c * 8, Qg + (long)(c & 63) * C + (c >> 6) * 8);
  }
  if (tid < 64) { mrun[tid] = -1e30f; lrun[tid] = 0.f; }
  __syncthreads();

  bf16x8 qf[2];
#pragma unroll
  for (int kk = 0; kk < 2; ++kk)
    qf[kk] = *(const bf16x8*)(Qs + ((kk * 4 + lk) * 64 + w * 16 + lrow) * 8);

  f32x4 o[4] = {};

  const int vrow = tid >> 2;
  const int vseg = (tid & 3) * 16;

  for (int kt = 0; kt < (int)T; kt += 64) {
    {
      int c = tid;
      gld16(Ks + c * 8, Kg0 + (long)(kt + (c & 63)) * C + (c >> 6) * 8);
      c = tid + 256;
      gld16(Ks + c * 8, Kg0 + (long)(kt + (c & 63)) * C + (c >> 6) * 8);
    }
    {
      const unsigned short* vg = Vg0 + (long)(kt + vrow) * C + vseg;
      bf16x8 v0 = *(const bf16x8*)(vg);
      bf16x8 v1 = *(const bf16x8*)(vg + 8);
#pragma unroll
      for (int i = 0; i < 8; ++i) Vt[(vseg + i) * 72 + vrow] = (unsigned short)v0[i];
#pragma unroll
      for (int i = 0; i < 8; ++i) Vt[(vseg + 8 + i) * 72 + vrow] = (unsigned short)v1[i];
    }
    __syncthreads();

    // S = Q K^T (scale already folded into Q)
    f32x4 s[4] = {};
#pragma unroll
    for (int kk = 0; kk < 2; ++kk) {
#pragma unroll
      for (int j = 0; j < 4; ++j) {
        bf16x8 kf = *(const bf16x8*)(Ks + ((kk * 4 + lk) * 64 + j * 16 + lrow) * 8);
        s[j] = __builtin_amdgcn_mfma_f32_16x16x32_bf16(qf[kk], kf, s[j], 0, 0, 0);
      }
    }
#pragma unroll
    for (int j = 0; j < 4; ++j)
#pragma unroll
      for (int r = 0; r < 4; ++r)
        Ss[(w * 16 + lk * 4 + r) * 66 + j * 16 + lrow] = s[j][r];
    __syncthreads();

    // online softmax: 4 threads per q-row
    {
      const int row = tid >> 2, seg = tid & 3;
      float sv[16]; float mloc = -1e30f;
#pragma unroll
      for (int i = 0; i < 16; ++i) {
        sv[i] = Ss[row * 66 + seg * 16 + i];
        mloc = fmaxf(mloc, sv[i]);
      }
      mloc = fmaxf(mloc, __shfl_xor(mloc, 1));
      mloc = fmaxf(mloc, __shfl_xor(mloc, 2));
      const float mprev = mrun[row];
      const float mnew = fmaxf(mprev, mloc);
      const float al = __expf(mprev - mnew);
      float ssum = 0.f;
      bf16x8 p0, p1;
#pragma unroll
      for (int i = 0; i < 8; ++i) {
        float p = __expf(sv[i] - mnew); ssum += p; p0[i] = (short)f2bf(p);
      }
#pragma unroll
      for (int i = 0; i < 8; ++i) {
        float p = __expf(sv[8 + i] - mnew); ssum += p; p1[i] = (short)f2bf(p);
      }
      *(bf16x8*)(Ps + row * 72 + seg * 16) = p0;
      *(bf16x8*)(Ps + row * 72 + seg * 16 + 8) = p1;
      ssum += __shfl_xor(ssum, 1);
      ssum += __shfl_xor(ssum, 2);
      if (seg == 0) {
        mrun[row] = mnew;
        lrun[row] = lrun[row] * al + ssum;
        alphas[row] = al;
      }
    }
    __syncthreads();

    // O = O*alpha + P V
    {
      float al_r[4];
#pragma unroll
      for (int r = 0; r < 4; ++r) al_r[r] = alphas[w * 16 + lk * 4 + r];
#pragma unroll
      for (int j = 0; j < 4; ++j)
#pragma unroll
        for (int r = 0; r < 4; ++r) o[j][r] *= al_r[r];
#pragma unroll
      for (int kk = 0; kk < 2; ++kk) {
        bf16x8 pa = *(const bf16x8*)(Ps + (w * 16 + lrow) * 72 + kk * 32 + lk * 8);
#pragma unroll
        for (int j = 0; j < 4; ++j) {
          bf16x8 vb = *(const bf16x8*)(Vt + (j * 16 + lrow) * 72 + kk * 32 + lk * 8);
          o[j] = __builtin_amdgcn_mfma_f32_16x16x32_bf16(pa, vb, o[j], 0, 0, 0);
        }
      }
    }
    __syncthreads();
  }

  unsigned short* Yg = Y + ((long)b * NQ + qt * 64) * C + h * 64;
  float linv[4];
#pragma unroll
  for (int r = 0; r < 4; ++r) linv[r] = 1.f / lrun[w * 16 + lk * 4 + r];
#pragma unroll
  for (int j = 0; j < 4; ++j)
#pragma unroll
    for (int r = 0; r < 4; ++r) {
      const int row = w * 16 + lk * 4 + r;
      Yg[(long)row * C + j * 16 + lrow] = f2bf(o[j][r] * linv[r]);
    }
}

// ---------------- launcher ----------------
extern "C" void kernel_launch(void* const* d_in, const int* in_sizes, int n_in,
                              void* d_out, int out_size, void* d_ws, size_t ws_size,
                              hipStream_t stream) {
  (void)in_sizes; (void)n_in; (void)out_size; (void)ws_size;
  const float* x   = (const float*)d_in[0];
  const float* enc = (const float*)d_in[1];
  const float* Wq  = (const float*)d_in[2];
  const float* bq  = (const float*)d_in[3];
  const float* Wk  = (const float*)d_in[4];
  const float* bk  = (const float*)d_in[5];
  const float* Wv  = (const float*)d_in[6];
  const float* bv  = (const float*)d_in[7];
  const float* Wp  = (const float*)d_in[8];
  const float* bp  = (const float*)d_in[9];

  const long M = 4L * 2048;   // 8192 rows
  const long C = 1024;

  char* ws = (char*)d_ws;
  size_t off = 0;
  auto alloc = [&](size_t bytes) {
    char* p = ws + off;
    off += (bytes + 255) & ~(size_t)255;
    return p;
  };
  unsigned short* Xb  = (unsigned short*)alloc(M * C * 2);
  unsigned short* Eb  = (unsigned short*)alloc(M * C * 2);
  unsigned short* Wqb = (unsigned short*)alloc(C * C * 2);
  unsigned short* Wkb = (unsigned short*)alloc(C * C * 2);
  unsigned short* Wvb = (unsigned short*)alloc(C * C * 2);
  unsigned short* Wpb = (unsigned short*)alloc(C * C * 2);
  unsigned short* Qw  = (unsigned short*)alloc(M * C * 2);
  unsigned short* Kw  = (unsigned short*)alloc(M * C * 2);
  unsigned short* Vw  = (unsigned short*)alloc(M * C * 2);
  unsigned short* Yb  = (unsigned short*)alloc(M * C * 2);

  // conversions
  {
    int n4 = (int)(M * C / 4);
    int blocks = (n4 + 255) / 256; if (blocks > 2048) blocks = 2048;
    cvt_kernel<<<blocks, 256, 0, stream>>>((const float4*)x,   (ushort4*)Xb, n4);
    cvt_kernel<<<blocks, 256, 0, stream>>>((const float4*)enc, (ushort4*)Eb, n4);
    int w4 = (int)(C * C / 4);
    int wblocks = (w4 + 255) / 256; if (wblocks > 2048) wblocks = 2048;
    cvt_kernel<<<wblocks, 256, 0, stream>>>((const float4*)Wq, (ushort4*)Wqb, w4);
    cvt_kernel<<<wblocks, 256, 0, stream>>>((const float4*)Wk, (ushort4*)Wkb, w4);
    cvt_kernel<<<wblocks, 256, 0, stream>>>((const float4*)Wv, (ushort4*)Wvb, w4);
    cvt_kernel<<<wblocks, 256, 0, stream>>>((const float4*)Wp, (ushort4*)Wpb, w4);
  }

  dim3 ggrid((unsigned)(C / 128), (unsigned)(M / 128));
  // Q = (x Wq^T + bq) * 1/sqrt(64)
  gemm_bt_kernel<<<ggrid, 256, 0, stream>>>(Xb, Wqb, bq, Qw, nullptr,
                                            (int)M, (int)C, (int)C, 0.125f);
  gemm_bt_kernel<<<ggrid, 256, 0, stream>>>(Eb, Wkb, bk, Kw, nullptr,
                                            (int)M, (int)C, (int)C, 1.0f);
  gemm_bt_kernel<<<ggrid, 256, 0, stream>>>(Eb, Wvb, bv, Vw, nullptr,
                                            (int)M, (int)C, (int)C, 1.0f);

  attn_kernel<<<dim3(32, 16, 4), 256, 0, stream>>>(Qw, Kw, Vw, Yb);

  gemm_bt_kernel<<<ggrid, 256, 0, stream>>>(Yb, Wpb, bp, nullptr, (float*)d_out,
                                            (int)M, (int)C, (int)C, 1.0f);
}

// Round 2
// 389.039 us; speedup vs baseline: 1.1344x; 1.1344x over previous
//
#include <hip/hip_runtime.h>

typedef short bf16x8 __attribute__((ext_vector_type(8)));
typedef float f32x4 __attribute__((ext_vector_type(4)));

#define AS1 __attribute__((address_space(1)))
#define AS3 __attribute__((address_space(3)))

__device__ __forceinline__ void gld16(void* lds, const void* g) {
  __builtin_amdgcn_global_load_lds((const AS1 unsigned int*)g,
                                   (AS3 unsigned int*)lds, 16, 0, 0);
}

__device__ __forceinline__ unsigned short f2bf(float f) {
  union { float f; unsigned int u; } c; c.f = f;
  return (unsigned short)((c.u + 0x7FFFu + ((c.u >> 16) & 1u)) >> 16);
}

// ---------------- fp32 -> bf16 conversion ----------------
__global__ void cvt_kernel(const float4* __restrict__ in, ushort4* __restrict__ out, int n4) {
  int i = blockIdx.x * blockDim.x + threadIdx.x;
  int stride = gridDim.x * blockDim.x;
  for (; i < n4; i += stride) {
    float4 v = in[i];
    ushort4 o;
    o.x = f2bf(v.x); o.y = f2bf(v.y); o.z = f2bf(v.z); o.w = f2bf(v.w);
    out[i] = o;
  }
}

// ---------------- NT GEMM: out[m][n] = (sum_k A[m][k]*W[n][k] + bias[n]) * scale ----
// 2-phase prefetch: double-buffered LDS, one barrier per K-step (T3 minimum recipe).
__global__ __launch_bounds__(256) void gemm_bt_kernel(
    const unsigned short* __restrict__ A,
    const unsigned short* __restrict__ W,
    const float* __restrict__ bias,
    unsigned short* __restrict__ outB,  // bf16 output (or null)
    float* __restrict__ outF,           // f32 output (or null)
    int M, int N, int K, float scale)
{
  __shared__ alignas(16) unsigned short As[2][4 * 128 * 8];  // [buf][kblk][row][8]
  __shared__ alignas(16) unsigned short Bs[2][4 * 128 * 8];

  const int tid = threadIdx.x;
  const int lane = tid & 63;
  const int w = tid >> 6;
  const int wr = (w >> 1) * 64;
  const int wc = (w & 1) * 64;
  const int lrow = lane & 15;
  const int lk = lane >> 4;
  const long m0 = (long)blockIdx.y * 128;
  const long n0 = (long)blockIdx.x * 128;

  f32x4 acc[4][4] = {};

  const int c0 = tid, c1 = tid + 256;
  const unsigned short* Ag0 = A + (m0 + (c0 & 127)) * (long)K + (c0 >> 7) * 8;
  const unsigned short* Ag1 = A + (m0 + (c1 & 127)) * (long)K + (c1 >> 7) * 8;
  const unsigned short* Wg0 = W + (n0 + (c0 & 127)) * (long)K + (c0 >> 7) * 8;
  const unsigned short* Wg1 = W + (n0 + (c1 & 127)) * (long)K + (c1 >> 7) * 8;

  const int arow = wr + lrow;
  const int brow = wc + lrow;
  const int nt = K >> 5;

  // stage tile 0 into buf 0
  gld16(As[0] + c0 * 8, Ag0);
  gld16(As[0] + c1 * 8, Ag1);
  gld16(Bs[0] + c0 * 8, Wg0);
  gld16(Bs[0] + c1 * 8, Wg1);

  int cur = 0;
  for (int t = 0; t < nt; ++t) {
    __syncthreads();  // drains vmcnt: buf[cur] ready; prev reads of buf[cur^1] done
    if (t + 1 < nt) {
      const int kt = (t + 1) * 32;
      gld16(As[cur ^ 1] + c0 * 8, Ag0 + kt);
      gld16(As[cur ^ 1] + c1 * 8, Ag1 + kt);
      gld16(Bs[cur ^ 1] + c0 * 8, Wg0 + kt);
      gld16(Bs[cur ^ 1] + c1 * 8, Wg1 + kt);
    }
    const unsigned short* as = As[cur];
    const unsigned short* bs = Bs[cur];
    bf16x8 af[4], bfr[4];
#pragma unroll
    for (int i = 0; i < 4; ++i)
      af[i] = *(const bf16x8*)(as + (lk * 128 + arow + i * 16) * 8);
#pragma unroll
    for (int j = 0; j < 4; ++j)
      bfr[j] = *(const bf16x8*)(bs + (lk * 128 + brow + j * 16) * 8);
#pragma unroll
    for (int i = 0; i < 4; ++i)
#pragma unroll
      for (int j = 0; j < 4; ++j)
        acc[i][j] = __builtin_amdgcn_mfma_f32_16x16x32_bf16(af[i], bfr[j], acc[i][j], 0, 0, 0);
    cur ^= 1;
  }

#pragma unroll
  for (int j = 0; j < 4; ++j) {
    const long col = n0 + wc + j * 16 + lrow;
    const float bv = bias[col];
#pragma unroll
    for (int i = 0; i < 4; ++i) {
#pragma unroll
      for (int r = 0; r < 4; ++r) {
        const long row = m0 + wr + i * 16 + lk * 4 + r;
        float v = (acc[i][j][r] + bv) * scale;
        if (outF) outF[row * (long)N + col] = v;
        else      outB[row * (long)N + col] = f2bf(v);
      }
    }
  }
}

// ---------------- Flash attention ----------------
// Q,K,V: [B][Seq][1024] bf16 (head h at channels h*64..h*64+63). Q pre-scaled by 1/8.
// Grid: (N/64, H, B), 256 threads (4 waves; wave w owns q-rows w*16..w*16+15).
// In-register softmax; swizzled Ps/Vt (16B-block XOR) — conflict-free stores;
// Vt double-buffered; async-stage split for next K (gld16) and V (reg).

// Vt layout: row d (64 ushorts = 128B); 16B-block index swizzled by (d ^ (d>>3))&7.
__device__ __forceinline__ int vt_off(int d, int t) {
  const int c = (d ^ (d >> 3)) & 7;
  return d * 64 + (((((t >> 3) ^ c) & 7) << 3) | (t & 7));
}
// Ps layout: row q; block swizzle by q&7.
__device__ __forceinline__ int ps_off(int q, int t) {
  return q * 64 + (((((t >> 3) ^ q) & 7) << 3) | (t & 7));
}

__global__ __launch_bounds__(256) void attn_kernel(
    const unsigned short* __restrict__ Q,
    const unsigned short* __restrict__ K,
    const unsigned short* __restrict__ V,
    unsigned short* __restrict__ Y)
{
  __shared__ alignas(16) unsigned short Ks[8 * 64 * 8];   // [dblk][t][8], linear (gld16)
  __shared__ alignas(16) unsigned short Vt[2][64 * 64];   // [d][t] swizzled
  __shared__ alignas(16) unsigned short Ps[64 * 64];      // [q][t] swizzled

  const int tid = threadIdx.x;
  const int lane = tid & 63;
  const int w = tid >> 6;
  const int lrow = lane & 15;
  const int lk = lane >> 4;
  const int b = blockIdx.z, h = blockIdx.y, qt = blockIdx.x;
  const long C = 1024, T = 2048, NQ = 2048;

  const unsigned short* Qg = Q + ((long)b * NQ + qt * 64) * C + h * 64;
  const unsigned short* Kg0 = K + (long)b * T * C + h * 64;
  const unsigned short* Vg0 = V + (long)b * T * C + h * 64;

  // stage K(0) into LDS
  {
    int c = tid;
    gld16(Ks + c * 8, Kg0 + (long)(c & 63) * C + (c >> 6) * 8);
    c = tid + 256;
    gld16(Ks + c * 8, Kg0 + (long)(c & 63) * C + (c >> 6) * 8);
  }
  // Q fragments straight from global (L2-resident)
  bf16x8 qf[2];
#pragma unroll
  for (int kk = 0; kk < 2; ++kk)
    qf[kk] = *(const bf16x8*)(Qg + (long)(w * 16 + lrow) * C + (kk * 4 + lk) * 8);

  // V(0) -> regs -> swizzled Vt[0]
  const int vrow = tid >> 2;            // t within tile
  const int vseg = (tid & 3) * 16;      // d base
  {
    const unsigned short* vgp = Vg0 + (long)vrow * C + vseg;
    bf16x8 v0 = *(const bf16x8*)(vgp);
    bf16x8 v1 = *(const bf16x8*)(vgp + 8);
    unsigned short* vt = Vt[0];
#pragma unroll
    for (int i = 0; i < 8; ++i) vt[vt_off(vseg + i, vrow)] = (unsigned short)v0[i];
#pragma unroll
    for (int i = 0; i < 8; ++i) vt[vt_off(vseg + 8 + i, vrow)] = (unsigned short)v1[i];
  }
  __syncthreads();

  f32x4 o[4] = {};
  float mr[4], lr[4];
#pragma unroll
  for (int r = 0; r < 4; ++r) { mr[r] = -1e30f; lr[r] = 0.f; }
  int cur = 0;

  for (int kt = 0; kt < (int)T; kt += 64) {
    // ---- S = Q K^T (scale folded into Q) ----
    f32x4 s[4] = {};
    __builtin_amdgcn_s_setprio(1);
#pragma unroll
    for (int kk = 0; kk < 2; ++kk) {
#pragma unroll
      for (int j = 0; j < 4; ++j) {
        bf16x8 kf = *(const bf16x8*)(Ks + ((kk * 4 + lk) * 64 + j * 16 + lrow) * 8);
        s[j] = __builtin_amdgcn_mfma_f32_16x16x32_bf16(qf[kk], kf, s[j], 0, 0, 0);
      }
    }
    __builtin_amdgcn_s_setprio(0);

    // ---- in-register online softmax (q-row spans one 16-lane group) ----
    float alpha[4];
#pragma unroll
    for (int r = 0; r < 4; ++r) {
      float m = fmaxf(fmaxf(s[0][r], s[1][r]), fmaxf(s[2][r], s[3][r]));
      m = fmaxf(m, __shfl_xor(m, 1));
      m = fmaxf(m, __shfl_xor(m, 2));
      m = fmaxf(m, __shfl_xor(m, 4));
      m = fmaxf(m, __shfl_xor(m, 8));
      const float mn = fmaxf(mr[r], m);
      alpha[r] = __expf(mr[r] - mn);
      mr[r] = mn;
      const int q = w * 16 + lk * 4 + r;
      float ls = 0.f;
#pragma unroll
      for (int j = 0; j < 4; ++j) {
        float p = __expf(s[j][r] - mn);
        ls += p;
        Ps[ps_off(q, j * 16 + lrow)] = f2bf(p);
      }
      lr[r] = lr[r] * alpha[r] + ls;  // lane-partial sum; reduced in epilogue
    }
    __syncthreads();  // Ps visible; Ks reads done

    // ---- prefetch next tile: K via gld16, V into regs (overlaps PV) ----
    const bool more = (kt + 64 < (int)T);
    bf16x8 nv0, nv1;
    if (more) {
      int c = tid;
      gld16(Ks + c * 8, Kg0 + (long)(kt + 64 + (c & 63)) * C + (c >> 6) * 8);
      c = tid + 256;
      gld16(Ks + c * 8, Kg0 + (long)(kt + 64 + (c & 63)) * C + (c >> 6) * 8);
      const unsigned short* vgn = Vg0 + (long)(kt + 64 + vrow) * C + vseg;
      nv0 = *(const bf16x8*)(vgn);
      nv1 = *(const bf16x8*)(vgn + 8);
    }

    // ---- O = O*alpha + P V ----
#pragma unroll
    for (int j = 0; j < 4; ++j)
#pragma unroll
      for (int r = 0; r < 4; ++r) o[j][r] *= alpha[r];

    const unsigned short* vt = Vt[cur];
    const int paq = w * 16 + lrow;
    __builtin_amdgcn_s_setprio(1);
#pragma unroll
    for (int kk = 0; kk < 2; ++kk) {
      const int tb = kk * 4 + lk;
      bf16x8 pa = *(const bf16x8*)(Ps + paq * 64 + (((tb ^ paq) & 7) << 3));
#pragma unroll
      for (int j = 0; j < 4; ++j) {
        const int d = j * 16 + lrow;
        const int cs = (d ^ (d >> 3)) & 7;
        bf16x8 vb = *(const bf16x8*)(vt + d * 64 + (((tb ^ cs) & 7) << 3));
        o[j] = __builtin_amdgcn_mfma_f32_16x16x32_bf16(pa, vb, o[j], 0, 0, 0);
      }
    }
    __builtin_amdgcn_s_setprio(0);

    // ---- write next V tile into the other Vt buffer ----
    if (more) {
      unsigned short* vtn = Vt[cur ^ 1];
#pragma unroll
      for (int i = 0; i < 8; ++i) vtn[vt_off(vseg + i, vrow)] = (unsigned short)nv0[i];
#pragma unroll
      for (int i = 0; i < 8; ++i) vtn[vt_off(vseg + 8 + i, vrow)] = (unsigned short)nv1[i];
    }
    cur ^= 1;
    __syncthreads();  // Vt[new cur] + Ks(next) ready; Ps reads done
  }

  // ---- epilogue: reduce l across the 16-lane group, normalize, store ----
  unsigned short* Yg = Y + ((long)b * NQ + qt * 64) * C + h * 64;
  float linv[4];
#pragma unroll
  for (int r = 0; r < 4; ++r) {
    float l = lr[r];
    l += __shfl_xor(l, 1);
    l += __shfl_xor(l, 2);
    l += __shfl_xor(l, 4);
    l += __shfl_xor(l, 8);
    linv[r] = 1.f / l;
  }
#pragma unroll
  for (int j = 0; j < 4; ++j)
#pragma unroll
    for (int r = 0; r < 4; ++r) {
      const int row = w * 16 + lk * 4 + r;
      Yg[(long)row * C + j * 16 + lrow] = f2bf(o[j][r] * linv[r]);
    }
}

// ---------------- launcher ----------------
extern "C" void kernel_launch(void* const* d_in, const int* in_sizes, int n_in,
                              void* d_out, int out_size, void* d_ws, size_t ws_size,
                              hipStream_t stream) {
  (void)in_sizes; (void)n_in; (void)out_size; (void)ws_size;
  const float* x   = (const float*)d_in[0];
  const float* enc = (const float*)d_in[1];
  const float* Wq  = (const float*)d_in[2];
  const float* bq  = (const float*)d_in[3];
  const float* Wk  = (const float*)d_in[4];
  const float* bk  = (const float*)d_in[5];
  const float* Wv  = (const float*)d_in[6];
  const float* bv  = (const float*)d_in[7];
  const float* Wp  = (const float*)d_in[8];
  const float* bp  = (const float*)d_in[9];

  const long M = 4L * 2048;   // 8192 rows
  const long C = 1024;

  char* ws = (char*)d_ws;
  size_t off = 0;
  auto alloc = [&](size_t bytes) {
    char* p = ws + off;
    off += (bytes + 255) & ~(size_t)255;
    return p;
  };
  unsigned short* Xb  = (unsigned short*)alloc(M * C * 2);
  unsigned short* Eb  = (unsigned short*)alloc(M * C * 2);
  unsigned short* Wqb = (unsigned short*)alloc(C * C * 2);
  unsigned short* Wkb = (unsigned short*)alloc(C * C * 2);
  unsigned short* Wvb = (unsigned short*)alloc(C * C * 2);
  unsigned short* Wpb = (unsigned short*)alloc(C * C * 2);
  unsigned short* Qw  = (unsigned short*)alloc(M * C * 2);
  unsigned short* Kw  = (unsigned short*)alloc(M * C * 2);
  unsigned short* Vw  = (unsigned short*)alloc(M * C * 2);
  unsigned short* Yb  = (unsigned short*)alloc(M * C * 2);

  // conversions
  {
    int n4 = (int)(M * C / 4);
    int blocks = (n4 + 255) / 256; if (blocks > 2048) blocks = 2048;
    cvt_kernel<<<blocks, 256, 0, stream>>>((const float4*)x,   (ushort4*)Xb, n4);
    cvt_kernel<<<blocks, 256, 0, stream>>>((const float4*)enc, (ushort4*)Eb, n4);
    int w4 = (int)(C * C / 4);
    int wblocks = (w4 + 255) / 256; if (wblocks > 2048) wblocks = 2048;
    cvt_kernel<<<wblocks, 256, 0, stream>>>((const float4*)Wq, (ushort4*)Wqb, w4);
    cvt_kernel<<<wblocks, 256, 0, stream>>>((const float4*)Wk, (ushort4*)Wkb, w4);
    cvt_kernel<<<wblocks, 256, 0, stream>>>((const float4*)Wv, (ushort4*)Wvb, w4);
    cvt_kernel<<<wblocks, 256, 0, stream>>>((const float4*)Wp, (ushort4*)Wpb, w4);
  }

  dim3 ggrid((unsigned)(C / 128), (unsigned)(M / 128));
  // Q = (x Wq^T + bq) * 1/sqrt(64)
  gemm_bt_kernel<<<ggrid, 256, 0, stream>>>(Xb, Wqb, bq, Qw, nullptr,
                                            (int)M, (int)C, (int)C, 0.125f);
  gemm_bt_kernel<<<ggrid, 256, 0, stream>>>(Eb, Wkb, bk, Kw, nullptr,
                                            (int)M, (int)C, (int)C, 1.0f);
  gemm_bt_kernel<<<ggrid, 256, 0, stream>>>(Eb, Wvb, bv, Vw, nullptr,
                                            (int)M, (int)C, (int)C, 1.0f);

  attn_kernel<<<dim3(32, 16, 4), 256, 0, stream>>>(Qw, Kw, Vw, Yb);

  gemm_bt_kernel<<<ggrid, 256, 0, stream>>>(Yb, Wpb, bp, nullptr, (float*)d_out,
                                            (int)M, (int)C, (int)C, 1.0f);
}